// Round 9
// baseline (100.911 us; speedup 1.0000x reference)
//
#include <hip/hip_runtime.h>

// Backwarp (tfa.image.dense_image_warp):
// out[b,y,x,c] = bilinear(image, y - flow[b,y,x,0], x - flow[b,y,x,1])
// floors clamped to [0, size-2], alphas clamped to [0,1].
//
// Layout (round 9): 16 lanes per pixel, 1 float4 chunk per lane per corner.
// Each wave = 4 pixels; every image load instruction covers 4 fully
// contiguous 256 B segments (vs 8x128 B in the 8-lane layout) -> half the
// memory transactions per pixel at identical HBM line traffic.

#define BB 4
#define HH 512
#define WW 512
#define CV 16        // float4 chunks per pixel (C=64)
#define NBLK 32768   // blocks; each covers 32 pixels (2 px/thread x 16)

typedef float f32x4 __attribute__((ext_vector_type(4)));
typedef float f32x2 __attribute__((ext_vector_type(2)));

__device__ __forceinline__ void addr_alpha(
    long long p, int c16, long long& i00, float& ay, float& ax, f32x2 fl)
{
    int x = (int)(p & (WW - 1));
    long long t = p >> 9;
    int y = (int)(t & (HH - 1));
    int b = (int)(t >> 9);

    float qy = (float)y - fl.x;
    float qx = (float)x - fl.y;
    float fy = fminf(fmaxf(floorf(qy), 0.0f), (float)(HH - 2));
    float fx = fminf(fmaxf(floorf(qx), 0.0f), (float)(WW - 2));
    ay = fminf(fmaxf(qy - fy, 0.0f), 1.0f);
    ax = fminf(fmaxf(qx - fx, 0.0f), 1.0f);
    int y0 = (int)fy;
    int x0 = (int)fx;
    i00 = (((long long)b * HH + y0) * WW + x0) * CV + c16;
}

__device__ __forceinline__ f32x4 bilerp(
    const f32x4* __restrict__ img4, long long i00, float ay, float ax)
{
    f32x4 tl = img4[i00];
    f32x4 tr = img4[i00 + CV];                   // x0+1 (+256 B)
    f32x4 bl = img4[i00 + (long long)WW * CV];   // y0+1
    f32x4 br = img4[i00 + (long long)WW * CV + CV];
    f32x4 top = tl + ax * (tr - tl);
    f32x4 bot = bl + ax * (br - bl);
    return top + ay * (bot - top);
}

__global__ __launch_bounds__(256) void backwarp_kernel(
    const float* __restrict__ image,
    const float* __restrict__ flow,
    float* __restrict__ out)
{
    // XCD-bijective swizzle: each XCD gets a contiguous 1/8 slab of the grid
    int bid = (int)blockIdx.x;
    int orig = (bid & 7) * (NBLK / 8) + (bid >> 3);

    long long pix_base = (long long)orig * 32;
    int c16 = (int)(threadIdx.x & 15);  // which float4 chunk (0..15)
    int pl  = (int)(threadIdx.x >> 4);  // pixel lane 0..15
    long long p0 = pix_base + pl;
    long long p1 = pix_base + 16 + pl;

    // flow loads up front (read-once: NT), p1's latency hides under p0's work
    const f32x2* flow2 = (const f32x2*)flow;
    f32x2 fl0 = __builtin_nontemporal_load(&flow2[p0]);
    f32x2 fl1 = __builtin_nontemporal_load(&flow2[p1]);

    const f32x4* img4 = (const f32x4*)image;
    f32x4* out4 = (f32x4*)out;

    long long i00_0, i00_1;
    float ay0, ax0, ay1, ax1;
    addr_alpha(p0, c16, i00_0, ay0, ax0, fl0);
    addr_alpha(p1, c16, i00_1, ay1, ax1, fl1);

    f32x4 r0 = bilerp(img4, i00_0, ay0, ax0);
    f32x4 r1 = bilerp(img4, i00_1, ay1, ax1);

    // write-once output: NT stores bypass L2 (round-5 A/B: +22%)
    __builtin_nontemporal_store(r0, &out4[p0 * CV + c16]);
    __builtin_nontemporal_store(r1, &out4[p1 * CV + c16]);
}

extern "C" void kernel_launch(void* const* d_in, const int* in_sizes, int n_in,
                              void* d_out, int out_size, void* d_ws, size_t ws_size,
                              hipStream_t stream) {
    const float* image = (const float*)d_in[0];
    const float* flow  = (const float*)d_in[1];
    float* out = (float*)d_out;

    backwarp_kernel<<<NBLK, 256, 0, stream>>>(image, flow, out);
}